// Round 7
// baseline (322.546 us; speedup 1.0000x reference)
//
#include <hip/hip_runtime.h>
#include <stdint.h>

// SIREN MLP 3->256->256->256->256->3, N=524288, fp32 in/out.
// R12: hidden layers use bf16 MFMA 32x32x16 (was 16x16x32): same FLOPs in
// HALF the MFMA instructions (64 vs 128 per wave-layer), -17% matrix-pipe
// time (8.07 vs 2x4.85 cyc), half the acc dependency chains. LDS bytes,
// W bytes, register shape (acc 64 + Wbuf 64) unchanged vs R5 (245us).
// h LDS layout: 16B unit u = k_octet*64 + pt (2048 units = 32KB), reads
// fully consecutive (conflict-free). Final layer stays 16x16x32, read
// remapped. Evidence base: R5 245us; R9/R10/R11 falsified occupancy,
// L2-bytes, and barrier-drain theories; kernel is at ~92% of the ~900TF
// 2-barrier-structure ceiling -> attack instruction/dep count.

typedef float    f32x4  __attribute__((ext_vector_type(4)));
typedef float    f32x16 __attribute__((ext_vector_type(16)));
typedef short    s16x8  __attribute__((ext_vector_type(8)));
typedef uint32_t u32x2  __attribute__((ext_vector_type(2)));
typedef uint32_t u32x4  __attribute__((ext_vector_type(4)));

#define INV2PI 0.15915494309189535f
#define L0SCALE 4.774648292756860f   /* 30/(2*pi) */
#define W4OFF 196608                 /* halfword offset of W4^T frag in ws */

__device__ __forceinline__ uint16_t f32_to_bf16(float f) {
    uint32_t u = __builtin_bit_cast(uint32_t, f);
    u += 0x7FFFu + ((u >> 16) & 1u);   // RNE
    return (uint16_t)(u >> 16);
}
__device__ __forceinline__ uint32_t pack_bf16x2(float lo, float hi) {
#if __has_builtin(__builtin_amdgcn_cvt_pk_bf16_f32)
    auto v = __builtin_amdgcn_cvt_pk_bf16_f32(lo, hi);   // lo -> low half
    return __builtin_bit_cast(uint32_t, v);
#else
    uint32_t a = __builtin_bit_cast(uint32_t, lo);
    uint32_t b = __builtin_bit_cast(uint32_t, hi);
    a += 0x7FFFu + ((a >> 16) & 1u);
    b += 0x7FFFu + ((b >> 16) & 1u);
    return (a >> 16) | (b & 0xFFFF0000u);
#endif
}
// sin with input in REVOLUTIONS (v_sin_f32); 1/(2pi) pre-folded into weights.
__device__ __forceinline__ float sin_rev(float r) {
    return __builtin_amdgcn_sinf(r);
}

// W1..W3 -> bf16 A-frag order for 32x32x16 (lane&31=row c&31, lane>>5=h,
// k = s*16 + h*8 + j), scaled by 1/(2pi):
//   hw = (((l*16 + s)*8 + g)*64 + h*32 + (c&31))*8 + j
//   with s=k>>4, h=(k>>3)&1, j=k&7, g=c>>5.
// W4 (3x256) -> zero-padded 16x16x32 B-frag (16 out-cols, 3 used), unscaled:
//   hw = W4OFF + (kc*64 + lane)*8 + j; value = n16<3 ? W4[n16][kc*32+q*8+j] : 0
__global__ void convert_weights(const float* __restrict__ W1,
                                const float* __restrict__ W2,
                                const float* __restrict__ W3,
                                const float* __restrict__ W4,
                                uint16_t* __restrict__ wsb) {
    int tid = blockIdx.x * blockDim.x + threadIdx.x;
    if (tid < 196608) {
        int l = tid >> 16;
        int r = tid & 65535;
        int c = r >> 8;        // out-chan 0..255
        int k = r & 255;       // in-chan 0..255
        const float* W = (l == 0) ? W1 : (l == 1) ? W2 : W3;
        int s = k >> 4, h = (k >> 3) & 1, j = k & 7, g = c >> 5;
        wsb[(((l * 16 + s) * 8 + g) * 64 + h * 32 + (c & 31)) * 8 + j] =
            f32_to_bf16(W[c * 256 + k] * INV2PI);
    } else if (tid < 200704) {
        int e = tid - 196608;              // 0..4095
        int kc = e >> 9, lane = (e >> 3) & 63, j = e & 7;
        int n16 = lane & 15, q = lane >> 4;
        float v = (n16 < 3) ? W4[n16 * 256 + kc * 32 + q * 8 + j] : 0.0f;
        wsb[W4OFF + (kc * 64 + lane) * 8 + j] = f32_to_bf16(v);
    }
}

// 256 threads = 4 waves, 64 points/block. Wave wid owns chans wid*64..+63
// as 2 ctiles of 32; pts as 2 ptiles of 32. (256,3): 3 blocks/CU, unified
// VGPR cap 170/wave; live ~= 64 acc + 64 Wbuf + 8 hf + addr ~= 150.
__global__ __launch_bounds__(256, 3) void siren_main(
    const float* __restrict__ x,
    const float* __restrict__ W0, const float* __restrict__ b0,
    const float* __restrict__ b1, const float* __restrict__ b2,
    const float* __restrict__ b3,
    const float* __restrict__ b4,
    const uint16_t* __restrict__ Wb,   // permuted W1..W3 + W4 frag
    float* __restrict__ out)
{
    __shared__ uint16_t h_lds[2048 * 8];   // 32 KB: unit u = k_octet*64 + pt

    const int tid  = threadIdx.x;
    const int lane = tid & 63;
    const int wid  = tid >> 6;
    const int n16  = lane & 15;
    const int q    = lane >> 4;
    const int la   = lane & 31;        // row/col within 32-tile
    const int h5   = lane >> 5;        // 0..1 (k-half)
    const int p0   = blockIdx.x * 64;

    // ------- Layer 0 (fp32): h1 = sin_rev( (30/2pi)*(W0 x + b0) ) ----------
    {
        float xv[4][3];
        #pragma unroll
        for (int rt = 0; rt < 4; ++rt) {
            const float* xp = x + (p0 + rt * 16 + n16) * 3;
            xv[rt][0] = xp[0]; xv[rt][1] = xp[1]; xv[rt][2] = xp[2];
        }
        #pragma unroll
        for (int oo = 0; oo < 2; ++oo) {
            const int octet = wid * 8 + oo * 4 + q;      // chan-octet 0..31
            const float* w0r = W0 + octet * 24;
            float wv[24];
            #pragma unroll
            for (int i = 0; i < 24; ++i) wv[i] = w0r[i] * L0SCALE;
            float bb[8];
            #pragma unroll
            for (int i = 0; i < 8; ++i) bb[i] = b0[octet * 8 + i] * L0SCALE;
            #pragma unroll
            for (int rt = 0; rt < 4; ++rt) {
                u32x4 pk;
                #pragma unroll
                for (int j2 = 0; j2 < 4; ++j2) {
                    float za = wv[(2*j2  )*3+0] * xv[rt][0] +
                               wv[(2*j2  )*3+1] * xv[rt][1] +
                               wv[(2*j2  )*3+2] * xv[rt][2] + bb[2*j2];
                    float zb = wv[(2*j2+1)*3+0] * xv[rt][0] +
                               wv[(2*j2+1)*3+1] * xv[rt][1] +
                               wv[(2*j2+1)*3+2] * xv[rt][2] + bb[2*j2+1];
                    pk[j2] = pack_bf16x2(sin_rev(za), sin_rev(zb));
                }
                // unit = octet*64 + pt, pt = rt*16 + n16
                *(u32x4*)&h_lds[(octet * 64 + rt * 16 + n16) * 8] = pk;
            }
        }
    }
    __syncthreads();

    // ------- Hidden layers (bf16 MFMA 32x32x16, D[chan][pt]) ----------------
    #pragma unroll
    for (int l = 0; l < 3; ++l) {
        const uint16_t* wsl = Wb + l * 65536;
        const float* bl = (l == 0) ? b1 : (l == 1) ? b2 : b3;

        // rotating phase double buffer of W A-frags (8 frags = 64 regs).
        // Phase = 4 k-steps (K=64). Prefetch next phase under current MFMA.
        s16x8 Wbuf[2][2][4];   // [buf][ctile][i]
        #pragma unroll
        for (int ct = 0; ct < 2; ++ct)
            #pragma unroll
            for (int i = 0; i < 4; ++i)
                Wbuf[0][ct][i] = *(const s16x8*)(wsl +
                    ((i * 8 + wid * 2 + ct) * 64 + lane) * 8);

        // acc init = bias (pre-scaled): row = ct*32 + 8Q + 4*h5 + m
        f32x16 acc[2][2];      // [ctile][ptile]
        #pragma unroll
        for (int ct = 0; ct < 2; ++ct) {
            f32x16 bv;
            #pragma unroll
            for (int Q = 0; Q < 4; ++Q) {
                f32x4 b4v = *(const f32x4*)&bl[wid * 64 + ct * 32 + 8 * Q + 4 * h5];
                b4v *= INV2PI;
                #pragma unroll
                for (int m = 0; m < 4; ++m) bv[Q * 4 + m] = b4v[m];
            }
            acc[ct][0] = bv;
            acc[ct][1] = bv;
        }

        #pragma unroll
        for (int kp = 0; kp < 4; ++kp) {      // phase = 4 k-steps
            const int cur = kp & 1, nxt = cur ^ 1;
            if (kp < 3) {                     // prefetch next phase under MFMA
                #pragma unroll
                for (int ct = 0; ct < 2; ++ct)
                    #pragma unroll
                    for (int i = 0; i < 4; ++i)
                        Wbuf[nxt][ct][i] = *(const s16x8*)(wsl +
                            (((kp * 4 + 4 + i) * 8 + wid * 2 + ct) * 64 + lane) * 8);
            }
            #pragma unroll
            for (int i = 0; i < 4; ++i) {
                const int s = kp * 4 + i;
                // B-frags: lane la = pt-in-tile, h5 = k-half; unit = (s*2+h5)*64 + pt
                s16x8 hf[2];
                #pragma unroll
                for (int pt = 0; pt < 2; ++pt)
                    hf[pt] = *(const s16x8*)&h_lds[
                        ((s * 2 + h5) * 64 + pt * 32 + la) * 8];
                #pragma unroll
                for (int ct = 0; ct < 2; ++ct)
                    #pragma unroll
                    for (int pt = 0; pt < 2; ++pt)
                        acc[ct][pt] = __builtin_amdgcn_mfma_f32_32x32x16_bf16(
                            Wbuf[cur][ct][i], hf[pt], acc[ct][pt], 0, 0, 0);
            }
        }
        __syncthreads();   // all h reads done before overwrite

        // epilogue: sin (bias already in acc), write h_next.
        // value row c = wid*64 + ct*32 + 8Q + 4*h5 + m, pt = pt*32 + la
        // -> unit = (c>>3)*64 + pt = (wid*8 + ct*4 + Q)*64 + pt, halfword 4*h5+m
        uint32_t* hw = (uint32_t*)h_lds;
        #pragma unroll
        for (int ct = 0; ct < 2; ++ct) {
            #pragma unroll
            for (int Q = 0; Q < 4; ++Q) {
                #pragma unroll
                for (int pt = 0; pt < 2; ++pt) {
                    float s0 = sin_rev(acc[ct][pt][Q * 4 + 0]);
                    float s1 = sin_rev(acc[ct][pt][Q * 4 + 1]);
                    float s2 = sin_rev(acc[ct][pt][Q * 4 + 2]);
                    float s3 = sin_rev(acc[ct][pt][Q * 4 + 3]);
                    int u = (wid * 8 + ct * 4 + Q) * 64 + pt * 32 + la;
                    u32x2 w2 = { pack_bf16x2(s0, s1), pack_bf16x2(s2, s3) };
                    *(u32x2*)&hw[u * 4 + h5 * 2] = w2;   // 8B write
                }
            }
        }
        __syncthreads();
    }

    // ------- Final layer via MFMA 16x16x32: out = W4 h4 + b4 ----------------
    // A-frag (m=pt): lane n16 = pt row, k = kc*32 + q*8 + j
    // -> octet kc*4+q, pt wid*16+n16 -> unit (kc*4+q)*64 + wid*16 + n16.
    {
        float bb4 = (n16 < 3) ? b4[n16] : 0.0f;
        f32x4 accF = { bb4, bb4, bb4, bb4 };
        #pragma unroll
        for (int kc = 0; kc < 8; ++kc) {
            s16x8 w4f = *(const s16x8*)(Wb + W4OFF + (kc * 64 + lane) * 8);
            s16x8 af  = *(const s16x8*)&h_lds[
                ((kc * 4 + q) * 64 + wid * 16 + n16) * 8];
            accF = __builtin_amdgcn_mfma_f32_16x16x32_bf16(af, w4f, accF, 0, 0, 0);
        }
        // D: row=q*4+r -> pt-in-tile (tile wid), col=n16 -> out-chan (3 used)
        if (n16 < 3) {
            #pragma unroll
            for (int r = 0; r < 4; ++r)
                out[(p0 + wid * 16 + q * 4 + r) * 3 + n16] = accF[r];
        }
    }
}

extern "C" void kernel_launch(void* const* d_in, const int* in_sizes, int n_in,
                              void* d_out, int out_size, void* d_ws, size_t ws_size,
                              hipStream_t stream) {
    const float* x  = (const float*)d_in[0];
    const float* W0 = (const float*)d_in[1];
    const float* b0 = (const float*)d_in[2];
    const float* W1 = (const float*)d_in[3];
    const float* b1 = (const float*)d_in[4];
    const float* W2 = (const float*)d_in[5];
    const float* b2 = (const float*)d_in[6];
    const float* W3 = (const float*)d_in[7];
    const float* b3 = (const float*)d_in[8];
    const float* W4 = (const float*)d_in[9];
    const float* b4 = (const float*)d_in[10];
    float* outp     = (float*)d_out;
    uint16_t* wsb   = (uint16_t*)d_ws;   // needs 402 KB

    hipLaunchKernelGGL(convert_weights, dim3(784), dim3(256), 0, stream,
                       W1, W2, W3, W4, wsb);
    hipLaunchKernelGGL(siren_main, dim3(8192), dim3(256), 0, stream,
                       x, W0, b0, b1, b2, b3, b4, wsb, outp);
}

// Round 8
// 298.430 us; speedup vs baseline: 1.0808x; 1.0808x over previous
//
#include <hip/hip_runtime.h>
#include <stdint.h>

// SIREN MLP 3->256->256->256->256->3, N=524288, fp32 in/out.
// siren_main: byte-identical to the R5 champion (246us): bf16 MFMA 16x16x32,
// D[chan][pt], W streams global->VGPR via 256B rotating kc-pair double
// buffer, h ping-pongs in 32KB LDS (conflict-free 16B-unit layout
// u=(kc*4+pt)*64+q*16+n16), bias pre-loaded in accumulators, (256,3).
// Falsified levers (R6-R12): occupancy (R9: 16w/CU null), L2 bytes (R10:
// 3x cut, worse), barrier vmcnt-drain (R11: lgkm-only barriers, null),
// MFMA issue count (R12: 32x32x16, worse). Structure is at its serial-sum
// floor ~590K cyc/CU.
// R13: the BENCH metric (300us) exceeds siren_main (246us) by ~54us in
// every round -- convert_weights' 2-byte scatter stores are the suspect.
// Rewritten OUTPUT-major: thread = one 16B output unit, permutation
// inverted, 8 consecutive W floats read per thread, one coalesced 16B
// store. 25088 threads (98 blocks) vs 200704.

typedef float    f32x4 __attribute__((ext_vector_type(4)));
typedef short    s16x8 __attribute__((ext_vector_type(8)));
typedef uint32_t u32x2 __attribute__((ext_vector_type(2)));
typedef uint32_t u32x4 __attribute__((ext_vector_type(4)));

#define INV2PI 0.15915494309189535f
#define L0SCALE 4.774648292756860f   /* 30/(2*pi) */
#define W4OFF 196608                 /* halfword offset of W4^T frag in ws */

__device__ __forceinline__ uint16_t f32_to_bf16(float f) {
    uint32_t u = __builtin_bit_cast(uint32_t, f);
    u += 0x7FFFu + ((u >> 16) & 1u);   // RNE
    return (uint16_t)(u >> 16);
}
__device__ __forceinline__ uint32_t pack_bf16x2(float lo, float hi) {
#if __has_builtin(__builtin_amdgcn_cvt_pk_bf16_f32)
    auto v = __builtin_amdgcn_cvt_pk_bf16_f32(lo, hi);   // lo -> low half
    return __builtin_bit_cast(uint32_t, v);
#else
    uint32_t a = __builtin_bit_cast(uint32_t, lo);
    uint32_t b = __builtin_bit_cast(uint32_t, hi);
    a += 0x7FFFu + ((a >> 16) & 1u);
    b += 0x7FFFu + ((b >> 16) & 1u);
    return (a >> 16) | (b & 0xFFFF0000u);
#endif
}
// sin with input in REVOLUTIONS (v_sin_f32); 1/(2pi) pre-folded into weights.
__device__ __forceinline__ float sin_rev(float r) {
    return __builtin_amdgcn_sinf(r);
}

// Output-major weight conversion (coalesced 16B stores, consecutive reads).
// W1..W3 region, unit u < 24576:  hw = u*8 + j, with
//   u = ((l*8+kc)*16 + cH)*64 + q*16 + n16;  c = cH*16+n16, k = kc*32+q*8+j
//   value = bf16(W_l[c*256+k] * INV2PI)   (A-frag order for 16x16x32)
// W4 region, e = u-24576 < 512:  hw = W4OFF + e*8 + j, e = kc*64 + lane,
//   n16 = lane&15, q = lane>>4;  value = n16<3 ? bf16(W4[n16*256+kc*32+q*8+j]) : 0
__global__ void convert_weights(const float* __restrict__ W1,
                                const float* __restrict__ W2,
                                const float* __restrict__ W3,
                                const float* __restrict__ W4,
                                uint16_t* __restrict__ wsb) {
    int u = blockIdx.x * blockDim.x + threadIdx.x;
    if (u < 24576) {
        int n16 = u & 15, q = (u >> 4) & 3, cH = (u >> 6) & 15,
            kc = (u >> 10) & 7, l = u >> 13;
        const float* W = (l == 0) ? W1 : (l == 1) ? W2 : W3;
        const float* src = W + (cH * 16 + n16) * 256 + kc * 32 + q * 8;
        u32x4 pk;
        #pragma unroll
        for (int j2 = 0; j2 < 4; ++j2)
            pk[j2] = pack_bf16x2(src[2 * j2] * INV2PI, src[2 * j2 + 1] * INV2PI);
        *(u32x4*)(wsb + u * 8) = pk;
    } else if (u < 25088) {
        int e = u - 24576;               // 0..511
        int lane = e & 63, kc = e >> 6;
        int n16 = lane & 15, q = lane >> 4;
        u32x4 pk = { 0u, 0u, 0u, 0u };
        if (n16 < 3) {
            const float* src = W4 + n16 * 256 + kc * 32 + q * 8;
            #pragma unroll
            for (int j2 = 0; j2 < 4; ++j2)
                pk[j2] = pack_bf16x2(src[2 * j2], src[2 * j2 + 1]);
        }
        *(u32x4*)(wsb + W4OFF + e * 8) = pk;
    }
}

// 256 threads = 4 waves, 64 points/block. Wave wid owns chans wid*64..+63.
// (256,3): 3 waves/SIMD -> 3 blocks/CU; unified VGPR cap 170/wave.
__global__ __launch_bounds__(256, 3) void siren_main(
    const float* __restrict__ x,
    const float* __restrict__ W0, const float* __restrict__ b0,
    const float* __restrict__ b1, const float* __restrict__ b2,
    const float* __restrict__ b3,
    const float* __restrict__ b4,
    const uint16_t* __restrict__ Wb,   // permuted W1..W3 + W4 frag
    float* __restrict__ out)
{
    __shared__ uint16_t h_lds[2048 * 8];   // 32 KB

    const int tid  = threadIdx.x;
    const int lane = tid & 63;
    const int wid  = tid >> 6;
    const int n16  = lane & 15;
    const int q    = lane >> 4;
    const int p0   = blockIdx.x * 64;

    // ------- Layer 0 (fp32): h1 = sin_rev( (30/2pi)*(W0 x + b0) ) ----------
    {
        float xv[4][3];
        #pragma unroll
        for (int rt = 0; rt < 4; ++rt) {
            const float* xp = x + (p0 + rt * 16 + n16) * 3;
            xv[rt][0] = xp[0]; xv[rt][1] = xp[1]; xv[rt][2] = xp[2];
        }
        #pragma unroll
        for (int oo = 0; oo < 2; ++oo) {
            const int octet = wid * 8 + oo * 4 + q;      // chan-octet 0..31
            const float* w0r = W0 + octet * 24;
            float wv[24];
            #pragma unroll
            for (int i = 0; i < 24; ++i) wv[i] = w0r[i] * L0SCALE;
            float bb[8];
            #pragma unroll
            for (int i = 0; i < 8; ++i) bb[i] = b0[octet * 8 + i] * L0SCALE;
            const int kc0 = octet >> 2, q0 = octet & 3;
            #pragma unroll
            for (int rt = 0; rt < 4; ++rt) {
                u32x4 pk;
                #pragma unroll
                for (int j2 = 0; j2 < 4; ++j2) {
                    float za = wv[(2*j2  )*3+0] * xv[rt][0] +
                               wv[(2*j2  )*3+1] * xv[rt][1] +
                               wv[(2*j2  )*3+2] * xv[rt][2] + bb[2*j2];
                    float zb = wv[(2*j2+1)*3+0] * xv[rt][0] +
                               wv[(2*j2+1)*3+1] * xv[rt][1] +
                               wv[(2*j2+1)*3+2] * xv[rt][2] + bb[2*j2+1];
                    pk[j2] = pack_bf16x2(sin_rev(za), sin_rev(zb));
                }
                *(u32x4*)&h_lds[((kc0 * 4 + rt) * 64 + q0 * 16 + n16) * 8] = pk;
            }
        }
    }
    __syncthreads();

    // ------- Hidden layers (bf16 MFMA, D[chan][pt]) -------------------------
    #pragma unroll
    for (int l = 0; l < 3; ++l) {
        const uint16_t* wsl = Wb + l * 65536;
        const float* bl = (l == 0) ? b1 : (l == 1) ? b2 : b3;

        // rotating kc-pair double buffer of W fragments (256B -> SSA)
        s16x8 Wbuf[2][2][4];   // [buf][kc-in-pair][chan-tile]
        #pragma unroll
        for (int kc2 = 0; kc2 < 2; ++kc2)
            #pragma unroll
            for (int t = 0; t < 4; ++t)
                Wbuf[0][kc2][t] = *(const s16x8*)(wsl + ((kc2 * 16 + wid * 4 + t) * 64 + lane) * 8);

        // acc init = bias (pre-scaled): rides the MFMA C input, no epilogue add
        f32x4 acc[4][4];       // [chan-tile t][pt-tile pt]
        #pragma unroll
        for (int t = 0; t < 4; ++t) {
            f32x4 bv = *(const f32x4*)&bl[wid * 64 + t * 16 + q * 4];
            bv *= INV2PI;
            #pragma unroll
            for (int pt = 0; pt < 4; ++pt) acc[t][pt] = bv;
        }

        #pragma unroll
        for (int kp = 0; kp < 4; ++kp) {      // kc pair index
            const int cur = kp & 1, nxt = cur ^ 1;
            if (kp < 3) {                     // prefetch next pair under MFMA
                #pragma unroll
                for (int kc2 = 0; kc2 < 2; ++kc2)
                    #pragma unroll
                    for (int t = 0; t < 4; ++t)
                        Wbuf[nxt][kc2][t] = *(const s16x8*)(wsl +
                            (((kp * 2 + 2 + kc2) * 16 + wid * 4 + t) * 64 + lane) * 8);
            }
            #pragma unroll
            for (int kc2 = 0; kc2 < 2; ++kc2) {
                const int kc = kp * 2 + kc2;
                s16x8 hf[4];   // B-frags: lane n16 = pt-in-tile, q = k-octet
                #pragma unroll
                for (int pt = 0; pt < 4; ++pt)
                    hf[pt] = *(const s16x8*)&h_lds[((kc * 4 + pt) * 64 + lane) * 8];
                #pragma unroll
                for (int t = 0; t < 4; ++t)
                    #pragma unroll
                    for (int pt = 0; pt < 4; ++pt)
                        acc[t][pt] = __builtin_amdgcn_mfma_f32_16x16x32_bf16(
                            Wbuf[cur][kc2][t], hf[pt], acc[t][pt], 0, 0, 0);
            }
        }
        __syncthreads();   // all h reads done before overwrite

        // epilogue: sin (bias already in acc), write h_next in B-frag layout
        uint32_t* hw = (uint32_t*)h_lds;
        #pragma unroll
        for (int t = 0; t < 4; ++t) {
            const int kcp = wid * 2 + (t >> 1);
            const int qp  = (t * 2 + (q >> 1)) & 3;
            #pragma unroll
            for (int pt = 0; pt < 4; ++pt) {
                float s0 = sin_rev(acc[t][pt][0]);
                float s1 = sin_rev(acc[t][pt][1]);
                float s2 = sin_rev(acc[t][pt][2]);
                float s3 = sin_rev(acc[t][pt][3]);
                int base = ((kcp * 4 + pt) * 64 + qp * 16 + n16) * 4 + (q & 1) * 2;
                u32x2 w2 = { pack_bf16x2(s0, s1), pack_bf16x2(s2, s3) };
                *(u32x2*)&hw[base] = w2;   // 8B write, r=0..3
            }
        }
        __syncthreads();
    }

    // ------- Final layer via MFMA: out = W4 h4 + b4 -------------------------
    // h4 LDS frag doubles as A (m=pt); W4^T frags loaded late (L2-resident)
    // to keep them out of the live range of the main loops.
    {
        float bb4 = (n16 < 3) ? b4[n16] : 0.0f;
        f32x4 accF = { bb4, bb4, bb4, bb4 };
        #pragma unroll
        for (int kc = 0; kc < 8; ++kc) {
            s16x8 w4f = *(const s16x8*)(Wb + W4OFF + (kc * 64 + lane) * 8);
            s16x8 af  = *(const s16x8*)&h_lds[((kc * 4 + wid) * 64 + lane) * 8];
            accF = __builtin_amdgcn_mfma_f32_16x16x32_bf16(af, w4f, accF, 0, 0, 0);
        }
        // D: row=q*4+r -> pt-in-tile (tile wid), col=n16 -> out-chan (3 used)
        if (n16 < 3) {
            #pragma unroll
            for (int r = 0; r < 4; ++r)
                out[(p0 + wid * 16 + q * 4 + r) * 3 + n16] = accF[r];
        }
    }
}

extern "C" void kernel_launch(void* const* d_in, const int* in_sizes, int n_in,
                              void* d_out, int out_size, void* d_ws, size_t ws_size,
                              hipStream_t stream) {
    const float* x  = (const float*)d_in[0];
    const float* W0 = (const float*)d_in[1];
    const float* b0 = (const float*)d_in[2];
    const float* W1 = (const float*)d_in[3];
    const float* b1 = (const float*)d_in[4];
    const float* W2 = (const float*)d_in[5];
    const float* b2 = (const float*)d_in[6];
    const float* W3 = (const float*)d_in[7];
    const float* b3 = (const float*)d_in[8];
    const float* W4 = (const float*)d_in[9];
    const float* b4 = (const float*)d_in[10];
    float* outp     = (float*)d_out;
    uint16_t* wsb   = (uint16_t*)d_ws;   // needs 402 KB

    hipLaunchKernelGGL(convert_weights, dim3(98), dim3(256), 0, stream,
                       W1, W2, W3, W4, wsb);
    hipLaunchKernelGGL(siren_main, dim3(8192), dim3(256), 0, stream,
                       x, W0, b0, b1, b2, b3, b4, wsb, outp);
}

// Round 9
// 278.307 us; speedup vs baseline: 1.1590x; 1.0723x over previous
//
#include <hip/hip_runtime.h>
#include <stdint.h>

// SIREN MLP 3->256->256->256->256->3, N=524288, fp32 in/out.
// siren_main R14: 256 threads / 4 waves per block, 128 POINTS per block
// (was 64). Per-wave tile 64ch x 128pt: acc[4][8]=128 VGPR, single-kc W
// double-buffer (32 VGPR), hf processed in two 4-tile halves (32 VGPR live),
// (256,2) cap=256, live ~212. h in 64KB LDS (unit u=(kc*8+pt)*64+q*16+n16),
// 2 blocks/CU = 2 sync groups.
// WHY: W1..W3 are re-streamed from L2 by every block (384KB/block). Serial-
// sum model says that's the largest term (~220K cyc/CU, 37%). R10 cut it 3x
// but confounded with 1-sync-group (+140K penalty). This halves W traffic
// at unchanged LDS/VALU/MFMA per point and keeps 2 groups -> clean test.
// Falsified so far: occupancy (R9), barrier vmcnt-drain (R11), MFMA issue
// count (R12), convert_weights scatter (R13: gap is harness overhead).
// convert_weights: output-major (R13), coalesced 16B stores.

typedef float    f32x4 __attribute__((ext_vector_type(4)));
typedef short    s16x8 __attribute__((ext_vector_type(8)));
typedef uint32_t u32x2 __attribute__((ext_vector_type(2)));
typedef uint32_t u32x4 __attribute__((ext_vector_type(4)));

#define INV2PI 0.15915494309189535f
#define L0SCALE 4.774648292756860f   /* 30/(2*pi) */
#define W4OFF 196608                 /* halfword offset of W4^T frag in ws */

__device__ __forceinline__ uint32_t pack_bf16x2(float lo, float hi) {
#if __has_builtin(__builtin_amdgcn_cvt_pk_bf16_f32)
    auto v = __builtin_amdgcn_cvt_pk_bf16_f32(lo, hi);   // lo -> low half
    return __builtin_bit_cast(uint32_t, v);
#else
    uint32_t a = __builtin_bit_cast(uint32_t, lo);
    uint32_t b = __builtin_bit_cast(uint32_t, hi);
    a += 0x7FFFu + ((a >> 16) & 1u);
    b += 0x7FFFu + ((b >> 16) & 1u);
    return (a >> 16) | (b & 0xFFFF0000u);
#endif
}
// sin with input in REVOLUTIONS (v_sin_f32); 1/(2pi) pre-folded into weights.
__device__ __forceinline__ float sin_rev(float r) {
    return __builtin_amdgcn_sinf(r);
}

// Output-major weight conversion (coalesced 16B stores, consecutive reads).
// W1..W3 region, unit u < 24576:  hw = u*8 + j, with
//   u = ((l*8+kc)*16 + cH)*64 + q*16 + n16;  c = cH*16+n16, k = kc*32+q*8+j
//   value = bf16(W_l[c*256+k] * INV2PI)   (A-frag order for 16x16x32)
// W4 region, e = u-24576 < 512:  hw = W4OFF + e*8 + j, e = kc*64 + lane,
//   n16 = lane&15, q = lane>>4;  value = n16<3 ? bf16(W4[n16*256+kc*32+q*8+j]) : 0
__global__ void convert_weights(const float* __restrict__ W1,
                                const float* __restrict__ W2,
                                const float* __restrict__ W3,
                                const float* __restrict__ W4,
                                uint16_t* __restrict__ wsb) {
    int u = blockIdx.x * blockDim.x + threadIdx.x;
    if (u < 24576) {
        int n16 = u & 15, q = (u >> 4) & 3, cH = (u >> 6) & 15,
            kc = (u >> 10) & 7, l = u >> 13;
        const float* W = (l == 0) ? W1 : (l == 1) ? W2 : W3;
        const float* src = W + (cH * 16 + n16) * 256 + kc * 32 + q * 8;
        u32x4 pk;
        #pragma unroll
        for (int j2 = 0; j2 < 4; ++j2)
            pk[j2] = pack_bf16x2(src[2 * j2] * INV2PI, src[2 * j2 + 1] * INV2PI);
        *(u32x4*)(wsb + u * 8) = pk;
    } else if (u < 25088) {
        int e = u - 24576;               // 0..511
        int lane = e & 63, kc = e >> 6;
        int n16 = lane & 15, q = lane >> 4;
        u32x4 pk = { 0u, 0u, 0u, 0u };
        if (n16 < 3) {
            const float* src = W4 + n16 * 256 + kc * 32 + q * 8;
            #pragma unroll
            for (int j2 = 0; j2 < 4; ++j2)
                pk[j2] = pack_bf16x2(src[2 * j2], src[2 * j2 + 1]);
        }
        *(u32x4*)(wsb + W4OFF + e * 8) = pk;
    }
}

// 256 threads = 4 waves, 128 points/block. Wave wid owns chans wid*64..+63
// across ALL 128 pts (8 pt-tiles of 16). (256,2): 2 blocks/CU (LDS 2x64KB),
// unified VGPR cap 256/wave; K-loop live ~= 128 acc + 32 Wbuf + 32 hf + addr.
__global__ __launch_bounds__(256, 2) void siren_main(
    const float* __restrict__ x,
    const float* __restrict__ W0, const float* __restrict__ b0,
    const float* __restrict__ b1, const float* __restrict__ b2,
    const float* __restrict__ b3,
    const float* __restrict__ b4,
    const uint16_t* __restrict__ Wb,   // permuted W1..W3 + W4 frag
    float* __restrict__ out)
{
    __shared__ uint16_t h_lds[4096 * 8];   // 64 KB: unit u=(kc*8+pt)*64+q*16+n16

    const int tid  = threadIdx.x;
    const int lane = tid & 63;
    const int wid  = tid >> 6;
    const int n16  = lane & 15;
    const int q    = lane >> 4;
    const int p0   = blockIdx.x * 128;     // 4096 * 128 = 524288 exact

    // ------- Layer 0 (fp32): h1 = sin_rev( (30/2pi)*(W0 x + b0) ) ----------
    {
        float xv[8][3];
        #pragma unroll
        for (int rt = 0; rt < 8; ++rt) {
            const float* xp = x + (p0 + rt * 16 + n16) * 3;
            xv[rt][0] = xp[0]; xv[rt][1] = xp[1]; xv[rt][2] = xp[2];
        }
        #pragma unroll
        for (int oo = 0; oo < 2; ++oo) {
            const int octet = wid * 8 + oo * 4 + q;      // chan-octet 0..31
            const float* w0r = W0 + octet * 24;
            float wv[24];
            #pragma unroll
            for (int i = 0; i < 24; ++i) wv[i] = w0r[i] * L0SCALE;
            float bb[8];
            #pragma unroll
            for (int i = 0; i < 8; ++i) bb[i] = b0[octet * 8 + i] * L0SCALE;
            const int kc0 = octet >> 2, q0 = octet & 3;
            #pragma unroll
            for (int rt = 0; rt < 8; ++rt) {
                u32x4 pk;
                #pragma unroll
                for (int j2 = 0; j2 < 4; ++j2) {
                    float za = wv[(2*j2  )*3+0] * xv[rt][0] +
                               wv[(2*j2  )*3+1] * xv[rt][1] +
                               wv[(2*j2  )*3+2] * xv[rt][2] + bb[2*j2];
                    float zb = wv[(2*j2+1)*3+0] * xv[rt][0] +
                               wv[(2*j2+1)*3+1] * xv[rt][1] +
                               wv[(2*j2+1)*3+2] * xv[rt][2] + bb[2*j2+1];
                    pk[j2] = pack_bf16x2(sin_rev(za), sin_rev(zb));
                }
                *(u32x4*)&h_lds[((kc0 * 8 + rt) * 64 + q0 * 16 + n16) * 8] = pk;
            }
        }
    }
    __syncthreads();

    // ------- Hidden layers (bf16 MFMA 16x16x32, D[chan][pt]) ----------------
    #pragma unroll
    for (int l = 0; l < 3; ++l) {
        const uint16_t* wsl = Wb + l * 65536;
        const float* bl = (l == 0) ? b1 : (l == 1) ? b2 : b3;

        // single-kc rotating double buffer of W A-frags (32 VGPR). Depth-1
        // prefetch: 32 MFMAs (~155cy) per kc cover most of the ~200cy L2 lat.
        s16x8 Wbuf[2][4];   // [buf][chan-tile]
        #pragma unroll
        for (int t = 0; t < 4; ++t)
            Wbuf[0][t] = *(const s16x8*)(wsl + ((wid * 4 + t) * 64 + lane) * 8);

        // acc init = bias (pre-scaled): rides the MFMA C input
        f32x4 acc[4][8];       // [chan-tile t][pt-tile pt]  = 128 VGPR
        #pragma unroll
        for (int t = 0; t < 4; ++t) {
            f32x4 bv = *(const f32x4*)&bl[wid * 64 + t * 16 + q * 4];
            bv *= INV2PI;
            #pragma unroll
            for (int pt = 0; pt < 8; ++pt) acc[t][pt] = bv;
        }

        #pragma unroll
        for (int kc = 0; kc < 8; ++kc) {
            const int cur = kc & 1, nxt = cur ^ 1;
            if (kc < 7) {                     // prefetch next kc under MFMA
                #pragma unroll
                for (int t = 0; t < 4; ++t)
                    Wbuf[nxt][t] = *(const s16x8*)(wsl +
                        (((kc + 1) * 16 + wid * 4 + t) * 64 + lane) * 8);
            }
            // half A: pt-tiles 0..3 (caps hf liveness at 32 VGPR)
            {
                s16x8 hf[4];
                #pragma unroll
                for (int pt = 0; pt < 4; ++pt)
                    hf[pt] = *(const s16x8*)&h_lds[((kc * 8 + pt) * 64 + lane) * 8];
                #pragma unroll
                for (int t = 0; t < 4; ++t)
                    #pragma unroll
                    for (int pt = 0; pt < 4; ++pt)
                        acc[t][pt] = __builtin_amdgcn_mfma_f32_16x16x32_bf16(
                            Wbuf[cur][t], hf[pt], acc[t][pt], 0, 0, 0);
            }
            // half B: pt-tiles 4..7
            {
                s16x8 hf[4];
                #pragma unroll
                for (int pt = 0; pt < 4; ++pt)
                    hf[pt] = *(const s16x8*)&h_lds[((kc * 8 + 4 + pt) * 64 + lane) * 8];
                #pragma unroll
                for (int t = 0; t < 4; ++t)
                    #pragma unroll
                    for (int pt = 0; pt < 4; ++pt)
                        acc[t][4 + pt] = __builtin_amdgcn_mfma_f32_16x16x32_bf16(
                            Wbuf[cur][t], hf[pt], acc[t][4 + pt], 0, 0, 0);
            }
        }
        __syncthreads();   // all h reads done before overwrite

        // epilogue: sin (bias already in acc), write h_next in B-frag layout.
        // chan c = wid*64 + t*16 + q*4 + r -> kcp = wid*2+(t>>1),
        // qp = (t*2+(q>>1))&3, j = (q&1)*4 + r.
        uint32_t* hw = (uint32_t*)h_lds;
        #pragma unroll
        for (int t = 0; t < 4; ++t) {
            const int kcp = wid * 2 + (t >> 1);
            const int qp  = (t * 2 + (q >> 1)) & 3;
            #pragma unroll
            for (int pt = 0; pt < 8; ++pt) {
                float s0 = sin_rev(acc[t][pt][0]);
                float s1 = sin_rev(acc[t][pt][1]);
                float s2 = sin_rev(acc[t][pt][2]);
                float s3 = sin_rev(acc[t][pt][3]);
                int base = ((kcp * 8 + pt) * 64 + qp * 16 + n16) * 4 + (q & 1) * 2;
                u32x2 w2 = { pack_bf16x2(s0, s1), pack_bf16x2(s2, s3) };
                *(u32x2*)&hw[base] = w2;   // 8B write, r=0..3
            }
        }
        __syncthreads();
    }

    // ------- Final layer via MFMA: out = W4 h4 + b4 -------------------------
    // 8 pt-tiles; wave wid handles tiles wid*2 and wid*2+1.
    {
        float bb4 = (n16 < 3) ? b4[n16] : 0.0f;
        f32x4 accF[2] = { { bb4, bb4, bb4, bb4 }, { bb4, bb4, bb4, bb4 } };
        #pragma unroll
        for (int kc = 0; kc < 8; ++kc) {
            s16x8 w4f = *(const s16x8*)(Wb + W4OFF + (kc * 64 + lane) * 8);
            #pragma unroll
            for (int hh = 0; hh < 2; ++hh) {
                s16x8 af = *(const s16x8*)&h_lds[
                    ((kc * 8 + wid * 2 + hh) * 64 + lane) * 8];
                accF[hh] = __builtin_amdgcn_mfma_f32_16x16x32_bf16(
                    af, w4f, accF[hh], 0, 0, 0);
            }
        }
        // D: row=q*4+r -> pt-in-tile (tile wid*2+hh), col=n16 -> out-chan
        if (n16 < 3) {
            #pragma unroll
            for (int hh = 0; hh < 2; ++hh)
                #pragma unroll
                for (int r = 0; r < 4; ++r)
                    out[(p0 + (wid * 2 + hh) * 16 + q * 4 + r) * 3 + n16] = accF[hh][r];
        }
    }
}

extern "C" void kernel_launch(void* const* d_in, const int* in_sizes, int n_in,
                              void* d_out, int out_size, void* d_ws, size_t ws_size,
                              hipStream_t stream) {
    const float* x  = (const float*)d_in[0];
    const float* W0 = (const float*)d_in[1];
    const float* b0 = (const float*)d_in[2];
    const float* W1 = (const float*)d_in[3];
    const float* b1 = (const float*)d_in[4];
    const float* W2 = (const float*)d_in[5];
    const float* b2 = (const float*)d_in[6];
    const float* W3 = (const float*)d_in[7];
    const float* b3 = (const float*)d_in[8];
    const float* W4 = (const float*)d_in[9];
    const float* b4 = (const float*)d_in[10];
    float* outp     = (float*)d_out;
    uint16_t* wsb   = (uint16_t*)d_ws;   // needs 402 KB

    hipLaunchKernelGGL(convert_weights, dim3(98), dim3(256), 0, stream,
                       W1, W2, W3, W4, wsb);
    hipLaunchKernelGGL(siren_main, dim3(4096), dim3(256), 0, stream,
                       x, W0, b0, b1, b2, b3, b4, wsb, outp);
}